// Round 4
// baseline (394.278 us; speedup 1.0000x reference)
//
#include <hip/hip_runtime.h>
#include <stdint.h>

#define LDIM 1024
#define DDIM 256
#define FDIM 32
#define NSEG 64
#define BM 64
#define BK 64

typedef __attribute__((ext_vector_type(4))) float f32x4;
typedef __attribute__((ext_vector_type(8))) short short8;
typedef __attribute__((ext_vector_type(4))) unsigned int u32x4;

__device__ __forceinline__ unsigned int pk2bf(float a, float b) {
  union { float f; unsigned int u; } x, y; x.f = a; y.f = b;
  unsigned int ua = x.u + 0x7FFFu + ((x.u >> 16) & 1u);
  unsigned int ub = y.u + 0x7FFFu + ((y.u >> 16) & 1u);
  return (ua >> 16) | (ub & 0xFFFF0000u);
}

__device__ __forceinline__ unsigned short f2bf(float f) {
  union { float f; unsigned int u; } v; v.f = f;
  unsigned int r = v.u + 0x7FFFu + ((v.u >> 16) & 1u);
  return (unsigned short)(r >> 16);
}

__device__ __forceinline__ short8 pack8(f32x4 a, f32x4 b) {
  union { u32x4 u; short8 s; } r;
  r.u[0] = pk2bf(a[0], a[1]); r.u[1] = pk2bf(a[2], a[3]);
  r.u[2] = pk2bf(b[0], b[1]); r.u[3] = pk2bf(b[2], b[3]);
  return r.s;
}

// ---- prep: W1^T (bf16) rows 0..255, (W1@Wa1)^T rows 256..287 into ws ----
__global__ void prep_w1t(const float* __restrict__ W1, const float* __restrict__ Wa1,
                         unsigned short* __restrict__ w1t) {
  __shared__ float rowf[DDIM];
  const int k = blockIdx.x;
  const int t = threadIdx.x;
  float v = W1[(size_t)k * DDIM + t];
  rowf[t] = v;
  w1t[(size_t)t * LDIM + k] = f2bf(v);
  __syncthreads();
  if (t < FDIM) {
    float a = 0.f;
    for (int c = 0; c < DDIM; ++c) a += rowf[c] * Wa1[c * FDIM + t];
    w1t[(size_t)(DDIM + t) * LDIM + k] = f2bf(a);
  }
}

// ---- prep: zero accumulators, bz = b1@Wa1 + ba1 ----
__global__ void prep_misc(const float* __restrict__ b1, const float* __restrict__ Wa1,
                          const float* __restrict__ ba1, float* __restrict__ bz,
                          float* __restrict__ acc_eh, float* __restrict__ accE) {
  const int b = blockIdx.x, t = threadIdx.x;
  acc_eh[b * DDIM + t] = 0.f;
  if (t == 0) accE[b] = 0.f;
  if (b == 0 && t < FDIM) {
    float a = ba1[t];
    for (int c = 0; c < DDIM; ++c) a += b1[c] * Wa1[c * FDIM + t];
    bz[t] = a;
  }
}

// ---- main fused kernel: reg-direct A + counted-vmcnt pipeline ----
__global__ __launch_bounds__(256, 3) void fused_main(
    const float* __restrict__ x, const int* __restrict__ idxs,
    const unsigned short* __restrict__ w1t, const float* __restrict__ bz,
    const float* __restrict__ Wa2, const float* __restrict__ ba2,
    float* __restrict__ acc_eh, float* __restrict__ accE)
{
  __shared__ __align__(16) unsigned char blds[288 * 128];    // 288 rows x 128B, XOR-swizzled
  __shared__ float logit_s[BM];
  __shared__ float e_s[BM];
  __shared__ int seg_s[BM];

  const int tid = threadIdx.x;
  const int lane = tid & 63;
  const int wid = tid >> 6;       // 0..3
  const int wr = wid >> 1;        // 0..1 : 32-row half
  const int wc = wid & 1;         // 0..1 : 144-col half
  const int g = lane >> 4;
  const int cl = lane & 15;
  const int row0 = blockIdx.x * BM;

  if (tid < BM) seg_s[tid] = idxs[row0 + tid];

  f32x4 acc[2][9];
  const f32x4 zero4 = {0.f, 0.f, 0.f, 0.f};
  #pragma unroll
  for (int m = 0; m < 2; ++m)
    #pragma unroll
    for (int n = 0; n < 9; ++n) acc[m][n] = zero4;

  const char* w1tb = (const char*)w1t;

  // A fragment-direct: lane's rows = row0 + wr*32 + m*16 + cl; k-chunk = kk*32 + g*8
  const float* a0 = x + (size_t)(row0 + wr * 32 + cl) * LDIM + g * 8;
  const float* a1 = a0 + (size_t)16 * LDIM;

  // staging regs (f32) for current tile's fragments
  f32x4 s00, s01, s02, s03, s10, s11, s12, s13;
  {
    s00 = *(const f32x4*)(a0);      s01 = *(const f32x4*)(a0 + 4);
    s02 = *(const f32x4*)(a0 + 32); s03 = *(const f32x4*)(a0 + 36);
    s10 = *(const f32x4*)(a1);      s11 = *(const f32x4*)(a1 + 4);
    s12 = *(const f32x4*)(a1 + 32); s13 = *(const f32x4*)(a1 + 36);
  }

  #pragma unroll 1
  for (int kt = 0; kt < 16; ++kt) {
    __builtin_amdgcn_s_barrier();   // buf consumed (all ds_reads retired pre-MFMA); no vmcnt drain
    // stage B(kt): 9 x global_load_lds (async, counted in vmcnt)
    #pragma unroll
    for (int j = 0; j < 9; ++j) {
      int byteoff = j * 4096 + tid * 16;
      int brow = byteoff >> 7;
      int bcolb = byteoff & 127;
      int srcb = brow * 2048 + kt * 128 + (bcolb ^ ((brow & 7) << 4));
      __builtin_amdgcn_global_load_lds(
          (const __attribute__((address_space(1))) unsigned int*)(w1tb + srcb),
          (__attribute__((address_space(3))) unsigned int*)(blds + j * 4096 + wid * 1024),
          16, 0, 0);
    }
    // convert A_cur -> bf16 frags (compiler waits only the A staging loads, vmcnt(9))
    short8 af00 = pack8(s00, s01);  // m=0, kk=0
    short8 af01 = pack8(s02, s03);  // m=0, kk=1
    short8 af10 = pack8(s10, s11);  // m=1, kk=0
    short8 af11 = pack8(s12, s13);  // m=1, kk=1
    // issue A_next into the (now dead) staging regs — stays in flight across the
    // barrier + MFMA phase (counted vmcnt below does NOT drain it)
    {
      int ktn = (kt < 15) ? (kt + 1) : 15;   // kt=15: re-read own tile (L2-hot, keeps count at 8)
      const float* p0 = a0 + ktn * 64;
      const float* p1 = a1 + ktn * 64;
      s00 = *(const f32x4*)(p0);      s01 = *(const f32x4*)(p0 + 4);
      s02 = *(const f32x4*)(p0 + 32); s03 = *(const f32x4*)(p0 + 36);
      s10 = *(const f32x4*)(p1);      s11 = *(const f32x4*)(p1 + 4);
      s12 = *(const f32x4*)(p1 + 32); s13 = *(const f32x4*)(p1 + 36);
    }
    // wait only the 9 B loads (8 A-prefetch remain outstanding), then barrier
    asm volatile("s_waitcnt vmcnt(8)\n\ts_barrier" ::: "memory");
    // MFMA phase: ds_read B frags + 36 MFMA
    #pragma unroll
    for (int kk = 0; kk < 2; ++kk) {
      #pragma unroll
      for (int n = 0; n < 9; ++n) {
        int brr = wc * 144 + n * 16 + cl;
        short8 bf = *(const short8*)(blds + brr * 128 + ((kk * 64 + g * 16) ^ ((brr & 7) << 4)));
        acc[0][n] = __builtin_amdgcn_mfma_f32_16x16x32_bf16(kk ? af01 : af00, bf, acc[0][n], 0, 0, 0);
        acc[1][n] = __builtin_amdgcn_mfma_f32_16x16x32_bf16(kk ? af11 : af10, bf, acc[1][n], 0, 0, 0);
      }
    }
  }

  // ---- logits: z lives in acc frags n=7 (f=cl) and n=8 (f=16+cl) of wc==1 waves ----
  if (wc == 1) {
    const float w2a = Wa2[cl], w2b = Wa2[16 + cl];
    const float bza = bz[cl], bzb = bz[16 + cl];
    #pragma unroll
    for (int m = 0; m < 2; ++m) {
      float p[4];
      #pragma unroll
      for (int q = 0; q < 4; ++q) {
        float ea = exp2f((acc[m][7][q] + bza) * 2.8853900817779268f);
        float eb = exp2f((acc[m][8][q] + bzb) * 2.8853900817779268f);
        p[q] = (1.f - 2.f / (ea + 1.f)) * w2a + (1.f - 2.f / (eb + 1.f)) * w2b;
      }
      #pragma unroll
      for (int mask = 1; mask <= 8; mask <<= 1)
        #pragma unroll
        for (int q = 0; q < 4; ++q) p[q] += __shfl_xor(p[q], mask);
      if (cl == 0) {
        #pragma unroll
        for (int q = 0; q < 4; ++q)
          logit_s[wr * 32 + m * 16 + g * 4 + q] = p[q];
      }
    }
  }
  __syncthreads();
  if (tid < BM) e_s[tid] = expf(logit_s[tid] + ba2[0]);
  __syncthreads();

  // ---- per-segment weighted accumulation of H columns + sum of e ----
  // NOTE: n-loop compile-time unrolled with wave-uniform predicate — runtime
  // indexing of acc[][] demotes it to scratch (rule #20; round-2 regression).
  const int smin = seg_s[0];
  const int smax = seg_s[BM - 1];
  float ev[8]; int sv[8];
  #pragma unroll
  for (int m = 0; m < 2; ++m)
    #pragma unroll
    for (int q = 0; q < 4; ++q) {
      int rl = wr * 32 + m * 16 + g * 4 + q;
      ev[m * 4 + q] = e_s[rl];
      sv[m * 4 + q] = seg_s[rl];
    }
  for (int s = smin; s <= smax; ++s) {
    float wv[8];
    #pragma unroll
    for (int i = 0; i < 8; ++i) wv[i] = (sv[i] == s) ? ev[i] : 0.f;
    #pragma unroll
    for (int n = 0; n < 9; ++n) {
      if (n < 7 || wc == 0) {          // wave-uniform; indices stay static
        float cs = 0.f;
        #pragma unroll
        for (int m = 0; m < 2; ++m)
          #pragma unroll
          for (int q = 0; q < 4; ++q)
            cs += wv[m * 4 + q] * acc[m][n][q];
        cs += __shfl_xor(cs, 16);
        cs += __shfl_xor(cs, 32);
        if (lane < 16) atomicAdd(&acc_eh[s * DDIM + wc * 144 + n * 16 + cl], cs);
      }
    }
    if (wid == 0) {
      float v = (seg_s[lane] == s) ? e_s[lane] : 0.f;
      #pragma unroll
      for (int mask = 1; mask <= 32; mask <<= 1) v += __shfl_xor(v, mask);
      if (lane == 0) atomicAdd(&accE[s], v);
    }
  }
}

// ---- finalize: M = acc/Sum_e + b1; proj = normalize(M@Wp + bp) ----
__global__ void finalize_k(const float* __restrict__ acc_eh, const float* __restrict__ accE,
                           const float* __restrict__ b1, const float* __restrict__ Wp,
                           const float* __restrict__ bp, float* __restrict__ out) {
  __shared__ float Ml[DDIM];
  const int s = blockIdx.x, t = threadIdx.x;
  const float E = accE[s];
  float m = 0.f;
  if (E > 0.f) m = acc_eh[s * DDIM + t] / E + b1[t];
  out[s * DDIM + t] = m;
  Ml[t] = m;
  __syncthreads();
  if (t < FDIM) {
    float p = bp[t];
    for (int c = 0; c < DDIM; ++c) p += Ml[c] * Wp[c * FDIM + t];
    float n2 = p * p;
    #pragma unroll
    for (int mask = 1; mask <= 16; mask <<= 1) n2 += __shfl_xor(n2, mask);
    out[NSEG * DDIM + s * FDIM + t] = p / fmaxf(sqrtf(n2), 1e-12f);
  }
}

extern "C" void kernel_launch(void* const* d_in, const int* in_sizes, int n_in,
                              void* d_out, int out_size, void* d_ws, size_t ws_size,
                              hipStream_t stream) {
  const float* x   = (const float*)d_in[0];
  const int*   idxs= (const int*)d_in[1];
  const float* W1  = (const float*)d_in[2];
  const float* b1  = (const float*)d_in[3];
  const float* Wa1 = (const float*)d_in[4];
  const float* ba1 = (const float*)d_in[5];
  const float* Wa2 = (const float*)d_in[6];
  const float* ba2 = (const float*)d_in[7];
  const float* Wp  = (const float*)d_in[8];
  const float* bp  = (const float*)d_in[9];
  float* out = (float*)d_out;

  char* ws = (char*)d_ws;
  unsigned short* w1t = (unsigned short*)ws;          // 288*1024 bf16 (alloc 320 rows)
  float* bz     = (float*)(ws + 655360);              // 32 f32
  float* acc_eh = (float*)(ws + 655488);              // 64*256 f32
  float* accE   = (float*)(ws + 721024);              // 64 f32

  const int n = in_sizes[1];                          // 262144 rows
  prep_w1t<<<LDIM, DDIM, 0, stream>>>(W1, Wa1, w1t);
  prep_misc<<<NSEG, DDIM, 0, stream>>>(b1, Wa1, ba1, bz, acc_eh, accE);
  fused_main<<<n / BM, 256, 0, stream>>>(x, idxs, w1t, bz, Wa2, ba2, acc_eh, accE);
  finalize_k<<<NSEG, DDIM, 0, stream>>>(acc_eh, accE, b1, Wp, bp, out);
}